// Round 11
// baseline (146.557 us; speedup 1.0000x reference)
//
#include <hip/hip_runtime.h>

#define N_TOK    32768
#define NEMBED   1024
#define SCALE    32.0f   // sqrt(1024)
#define NTHREADS 512     // 8 waves per block

// persistent grid: 512 blocks; 32 KB LDS + <=64 VGPR -> 4 blocks/CU, 32 waves/CU.
// partition by wave-chunk cycles (~16.5K cyc each): b1 644M MAC, b2 1288M, b3 135M.
#define G0 24
#define G1 152   // %4==0 (cs x4: 256-col slices)
#define G2 304   // %8==0 (cs x8: 128-col slices)
#define G3 32    // %8==0
#define GRID (G0 + G1 + G2 + G3)   // 512

__device__ __forceinline__ int bucket_of(int idx) {
    return (idx < 20000) ? 0 : (idx < 40000) ? 1 : (idx < 200000) ? 2 : 3;
}
__device__ __forceinline__ int rfl(int v) { return __builtin_amdgcn_readfirstlane(v); }

// ---------------- classify + compact tokens into per-bucket lists ----------------
__global__ void classify_kernel(const int* __restrict__ x,
                                int* __restrict__ cnt,      // [4]
                                int* __restrict__ lists) {  // [4][N_TOK]
    __shared__ int s_cnt[4], s_base[4];
    int tid = threadIdx.x;
    if (tid < 4) s_cnt[tid] = 0;
    __syncthreads();
    int t = blockIdx.x * blockDim.x + tid;
    int b = 0, p = 0;
    if (t < N_TOK) {
        b = bucket_of(x[t]);
        p = atomicAdd(&s_cnt[b], 1);
    }
    __syncthreads();
    if (tid < 4) s_base[tid] = atomicAdd(&cnt[tid], s_cnt[tid]);
    __syncthreads();
    if (t < N_TOK) lists[b * N_TOK + s_base[b] + p] = t;
}

// ---------------- bucket 0: per-wave row copy (ids in SGPR, no LDS/barriers) ------
__device__ __forceinline__ void run_copy(const int* __restrict__ x,
                                         const float* __restrict__ table0,
                                         const int* __restrict__ list0,
                                         float* __restrict__ out,
                                         int n, int wv0, int nwv) {
    int lane = threadIdx.x & 63;
    const float4* t4 = (const float4*)table0;
    float4* o4 = (float4*)out;
    #pragma unroll 1
    for (int i = wv0; i < n; i += nwv) {
        int tok = rfl(list0[i]);
        int row = rfl(x[tok]);
        #pragma unroll
        for (int q = 0; q < 4; ++q) {
            float4 v = t4[(size_t)row * 256 + q * 64 + lane];
            v.x *= SCALE; v.y *= SCALE; v.z *= SCALE; v.w *= SCALE;
            o4[(size_t)tok * 256 + q * 64 + lane] = v;
        }
    }
}

// ------ buckets 2/3: 128-col P slice in LDS (pair layout); E wave-uniform loads ----
// cs in [0,8): cols [cs*128, +128); lane owns 2 cols (float2). Wave chunk = 8 tokens.
// PL[k2*64+l] = (P[2k2][c0], P[2k2][c1], P[2k2+1][c0], P[2k2+1][c1]), c0=cs*128+2l.
template <int D>
__device__ __forceinline__ void run_proj_reg(const int* __restrict__ x,
                                             const float* __restrict__ table,
                                             const float* __restrict__ proj,
                                             const int* __restrict__ list_b,
                                             float* __restrict__ out,
                                             int n, int start,
                                             int cs, int wv0, int nwv,
                                             float4* __restrict__ PL) {
    constexpr int D4 = D / 4, D2 = D / 2;
    int tid = threadIdx.x, lane = tid & 63;
    const float4* tb4 = (const float4*)table;

    // one-time cooperative P staging, single barrier
    #pragma unroll 1
    for (int idx = tid; idx < D2 * 64; idx += NTHREADS) {
        int k2 = idx >> 6, l = idx & 63;
        const float* r0 = &proj[(size_t)(2 * k2) * NEMBED + cs * 128 + 2 * l];
        const float* r1 = r0 + NEMBED;
        PL[idx] = make_float4(r0[0], r0[1], r1[0], r1[1]);
    }
    __syncthreads();

    int nch = (n + 7) >> 3;
    #pragma unroll 1
    for (int c = wv0; c < nch; c += nwv) {
        int toks[8], rows[8];
        #pragma unroll
        for (int j = 0; j < 8; ++j) {
            int i = c * 8 + j;
            toks[j] = rfl((i < n) ? list_b[i] : -1);
        }
        #pragma unroll
        for (int j = 0; j < 8; ++j)
            rows[j] = (toks[j] >= 0) ? rfl(x[toks[j]] - start) : 0;

        float2 acc[8];
        #pragma unroll
        for (int j = 0; j < 8; ++j) acc[j] = make_float2(0.f, 0.f);

        #pragma unroll 2
        for (int kg = 0; kg < D4; ++kg) {
            float4 pa = PL[(2 * kg + 0) * 64 + lane];   // k-rows 4kg, 4kg+1
            float4 pb = PL[(2 * kg + 1) * 64 + lane];   // k-rows 4kg+2, 4kg+3
            #pragma unroll
            for (int j = 0; j < 8; ++j) {
                float4 e = tb4[(size_t)rows[j] * D4 + kg];   // wave-uniform -> scalar path
                acc[j].x += e.x * pa.x + e.y * pa.z + e.z * pb.x + e.w * pb.z;
                acc[j].y += e.x * pa.y + e.y * pa.w + e.z * pb.y + e.w * pb.w;
            }
        }

        #pragma unroll
        for (int j = 0; j < 8; ++j) {
            if (toks[j] >= 0) {
                float2 v = make_float2(acc[j].x * SCALE, acc[j].y * SCALE);
                *(float2*)&out[(size_t)toks[j] * NEMBED + cs * 128 + 2 * lane] = v;
            }
        }
    }
}

// ------ bucket 1: D=256; P slice streamed through LDS in 16-row dbuf pieces -------
// cs in [0,4): cols [cs*256, +256). Block chunk = 64 tokens (8 waves x 8).
__device__ __forceinline__ void run_proj_stream(const int* __restrict__ x,
                                                const float* __restrict__ table,
                                                const float* __restrict__ proj,
                                                const int* __restrict__ list_b,
                                                float* __restrict__ out,
                                                int n, int start,
                                                int cs, int blk0, int nblk,
                                                float4* __restrict__ PL) {  // 2x1024 f4
    int tid = threadIdx.x, lane = tid & 63, w = tid >> 6;
    const float4* pj4 = (const float4*)proj;
    const float4* tb4 = (const float4*)table;
    int nch = (n + 63) >> 6;

    #pragma unroll 1
    for (int c = blk0; c < nch; c += nblk) {
        int toks[8], rows[8];
        #pragma unroll
        for (int j = 0; j < 8; ++j) {
            int i = c * 64 + w * 8 + j;
            toks[j] = rfl((i < n) ? list_b[i] : -1);
        }
        #pragma unroll
        for (int j = 0; j < 8; ++j)
            rows[j] = (toks[j] >= 0) ? rfl(x[toks[j]] - start) : 0;

        float4 acc[8];
        #pragma unroll
        for (int j = 0; j < 8; ++j) acc[j] = make_float4(0.f, 0.f, 0.f, 0.f);

        int i0 = tid * 2, i1 = tid * 2 + 1;
        // prologue: stage piece 0 -> buf 0
        float4 s0 = pj4[(size_t)(i0 >> 6) * 256 + cs * 64 + (i0 & 63)];
        float4 s1 = pj4[(size_t)(i1 >> 6) * 256 + cs * 64 + (i1 & 63)];
        PL[i0] = s0; PL[i1] = s1;
        __syncthreads();

        #pragma unroll 1
        for (int p = 0; p < 16; ++p) {
            const float4* cur = PL + (p & 1) * 1024;
            if (p < 15) {   // issue next-piece loads early (hidden under FMA)
                int base = (p + 1) * 16;
                s0 = pj4[(size_t)(base + (i0 >> 6)) * 256 + cs * 64 + (i0 & 63)];
                s1 = pj4[(size_t)(base + (i1 >> 6)) * 256 + cs * 64 + (i1 & 63)];
            }
            #pragma unroll 2
            for (int g = 0; g < 4; ++g) {
                float4 p0 = cur[(4 * g + 0) * 64 + lane];
                float4 p1 = cur[(4 * g + 1) * 64 + lane];
                float4 p2 = cur[(4 * g + 2) * 64 + lane];
                float4 p3 = cur[(4 * g + 3) * 64 + lane];
                #pragma unroll
                for (int j = 0; j < 8; ++j) {
                    float4 e = tb4[(size_t)rows[j] * 64 + p * 4 + g];  // wave-uniform
                    acc[j].x += e.x * p0.x + e.y * p1.x + e.z * p2.x + e.w * p3.x;
                    acc[j].y += e.x * p0.y + e.y * p1.y + e.z * p2.y + e.w * p3.y;
                    acc[j].z += e.x * p0.z + e.y * p1.z + e.z * p2.z + e.w * p3.z;
                    acc[j].w += e.x * p0.w + e.y * p1.w + e.z * p2.w + e.w * p3.w;
                }
            }
            if (p < 15) {   // commit next piece to the other buffer
                float4* nb = PL + ((p + 1) & 1) * 1024;
                nb[i0] = s0; nb[i1] = s1;
            }
            __syncthreads();
        }

        #pragma unroll
        for (int j = 0; j < 8; ++j) {
            if (toks[j] >= 0) {
                float4 v = acc[j];
                v.x *= SCALE; v.y *= SCALE; v.z *= SCALE; v.w *= SCALE;
                *(float4*)&out[(size_t)toks[j] * NEMBED + cs * 256 + lane * 4] = v;
            }
        }
    }
}

// ---------------- fused kernel: static block partition ----------------
__global__ __launch_bounds__(NTHREADS, 8)   // VGPR cap 64; 32 KB LDS -> 4 blocks/CU
void fused_embed_kernel(const int* __restrict__ x,
                        const float* __restrict__ t0, const float* __restrict__ t1,
                        const float* __restrict__ t2, const float* __restrict__ t3,
                        const float* __restrict__ p1, const float* __restrict__ p2,
                        const float* __restrict__ p3,
                        const int* __restrict__ cnt,
                        const int* __restrict__ lists,
                        float* __restrict__ out) {
    __shared__ __align__(16) float4 PL[2048];   // 32 KB
    int bid = blockIdx.x;
    int w = threadIdx.x >> 6;

    if (bid < G0) {
        run_copy(x, t0, lists, out, cnt[0], bid * 8 + w, G0 * 8);
    } else if (bid < G0 + G1) {
        int lb = bid - G0;
        run_proj_stream(x, t1, p1, lists + 1 * N_TOK, out, cnt[1], 20000,
                        lb & 3, lb >> 2, G1 / 4, PL);
    } else if (bid < G0 + G1 + G2) {
        int lb = bid - (G0 + G1);
        run_proj_reg<64>(x, t2, p2, lists + 2 * N_TOK, out, cnt[2], 40000,
                         lb & 7, (lb >> 3) * 8 + w, (G2 / 8) * 8, PL);
    } else {
        int lb = bid - (G0 + G1 + G2);
        run_proj_reg<16>(x, t3, p3, lists + 3 * N_TOK, out, cnt[3], 200000,
                         lb & 7, (lb >> 3) * 8 + w, (G3 / 8) * 8, PL);
    }
}

extern "C" void kernel_launch(void* const* d_in, const int* in_sizes, int n_in,
                              void* d_out, int out_size, void* d_ws, size_t ws_size,
                              hipStream_t stream) {
    const int*   x  = (const int*)d_in[0];
    const float* t0 = (const float*)d_in[1];
    const float* t1 = (const float*)d_in[2];
    const float* t2 = (const float*)d_in[3];
    const float* t3 = (const float*)d_in[4];
    const float* p1 = (const float*)d_in[5];
    const float* p2 = (const float*)d_in[6];
    const float* p3 = (const float*)d_in[7];
    float* out = (float*)d_out;

    int* cnt   = (int*)d_ws;
    int* lists = cnt + 64;

    hipMemsetAsync(d_ws, 0, 64 * sizeof(int), stream);
    classify_kernel<<<N_TOK / 256, 256, 0, stream>>>(x, cnt, lists);

    fused_embed_kernel<<<GRID, NTHREADS, 0, stream>>>(x, t0, t1, t2, t3, p1, p2, p3,
                                                      cnt, lists, out);
}

// Round 12
// 122.930 us; speedup vs baseline: 1.1922x; 1.1922x over previous
//
#include <hip/hip_runtime.h>

#define N_TOK    32768
#define NEMBED   1024
#define SCALE    32.0f   // sqrt(1024)
#define NTHREADS 512     // 8 waves per block

// 1024 blocks = 4 blocks/CU (32 KB LDS, VGPR<=64 -> 8 waves/SIMD), one generation.
// partition tuned so proj waves carry ~8.3K issue-cycles each:
#define G0 52
#define G1 308   // %4==0 (cs x4: 256-col slices), ~1 tile per block
#define G2 600   // %8==0 (cs x8: 128-col slices)
#define G3 64    // %8==0
#define GRID (G0 + G1 + G2 + G3)   // 1024

__device__ __forceinline__ int bucket_of(int idx) {
    return (idx < 20000) ? 0 : (idx < 40000) ? 1 : (idx < 200000) ? 2 : 3;
}
__device__ __forceinline__ int rfl(int v) { return __builtin_amdgcn_readfirstlane(v); }

// ---------------- classify + compact tokens into per-bucket lists ----------------
__global__ void classify_kernel(const int* __restrict__ x,
                                int* __restrict__ cnt,      // [4]
                                int* __restrict__ lists) {  // [4][N_TOK]
    __shared__ int s_cnt[4], s_base[4];
    int tid = threadIdx.x;
    if (tid < 4) s_cnt[tid] = 0;
    __syncthreads();
    int t = blockIdx.x * blockDim.x + tid;
    int b = 0, p = 0;
    if (t < N_TOK) {
        b = bucket_of(x[t]);
        p = atomicAdd(&s_cnt[b], 1);
    }
    __syncthreads();
    if (tid < 4) s_base[tid] = atomicAdd(&cnt[tid], s_cnt[tid]);
    __syncthreads();
    if (t < N_TOK) lists[b * N_TOK + s_base[b] + p] = t;
}

// ---------------- bucket 0: per-wave row copy (ids in SGPR, no LDS/barriers) ------
__device__ __forceinline__ void run_copy(const int* __restrict__ x,
                                         const float* __restrict__ table0,
                                         const int* __restrict__ list0,
                                         float* __restrict__ out,
                                         int n, int wv0, int nwv) {
    int lane = threadIdx.x & 63;
    const float4* t4 = (const float4*)table0;
    float4* o4 = (float4*)out;
    #pragma unroll 1
    for (int i = wv0; i < n; i += nwv) {
        int tok = rfl(list0[i]);
        int row = rfl(x[tok]);
        #pragma unroll
        for (int q = 0; q < 4; ++q) {
            float4 v = t4[(size_t)row * 256 + q * 64 + lane];
            v.x *= SCALE; v.y *= SCALE; v.z *= SCALE; v.w *= SCALE;
            o4[(size_t)tok * 256 + q * 64 + lane] = v;
        }
    }
}

// ------ buckets 2/3: 128-col P slice in LDS (pair layout, 32 KB max); E via SGPR ----
// cs in [0,8): cols [cs*128, +128); lane owns 2 cols (float2). Wave chunk = 8 tokens.
// PL[k2*64+l] = (P[2k2][c0], P[2k2][c1], P[2k2+1][c0], P[2k2+1][c1]), c0=cs*128+2l.
template <int D>
__device__ __forceinline__ void run_proj_reg(const int* __restrict__ x,
                                             const float* __restrict__ table,
                                             const float* __restrict__ proj,
                                             const int* __restrict__ list_b,
                                             float* __restrict__ out,
                                             int n, int start,
                                             int cs, int wv0, int nwv,
                                             float4* __restrict__ PL) {
    constexpr int D4 = D / 4, D2 = D / 2;
    int tid = threadIdx.x, lane = tid & 63;
    const float4* tb4 = (const float4*)table;

    // one-time cooperative P staging, single barrier
    #pragma unroll 1
    for (int idx = tid; idx < D2 * 64; idx += NTHREADS) {
        int k2 = idx >> 6, l = idx & 63;
        const float* r0 = &proj[(size_t)(2 * k2) * NEMBED + cs * 128 + 2 * l];
        const float* r1 = r0 + NEMBED;
        PL[idx] = make_float4(r0[0], r0[1], r1[0], r1[1]);
    }
    __syncthreads();

    int nch = (n + 7) >> 3;
    #pragma unroll 1
    for (int c = wv0; c < nch; c += nwv) {
        int toks[8], rows[8];
        #pragma unroll
        for (int j = 0; j < 8; ++j) {
            int i = c * 8 + j;
            toks[j] = rfl((i < n) ? list_b[i] : -1);
        }
        #pragma unroll
        for (int j = 0; j < 8; ++j)
            rows[j] = (toks[j] >= 0) ? rfl(x[toks[j]] - start) : 0;

        float2 acc[8];
        #pragma unroll
        for (int j = 0; j < 8; ++j) acc[j] = make_float2(0.f, 0.f);

        #pragma unroll 2
        for (int kg = 0; kg < D4; ++kg) {
            float4 pa = PL[(2 * kg + 0) * 64 + lane];   // k-rows 4kg, 4kg+1
            float4 pb = PL[(2 * kg + 1) * 64 + lane];   // k-rows 4kg+2, 4kg+3
            #pragma unroll
            for (int j = 0; j < 8; ++j) {
                float4 e = tb4[(size_t)rows[j] * D4 + kg];   // wave-uniform -> scalar path
                acc[j].x += e.x * pa.x + e.y * pa.z + e.z * pb.x + e.w * pb.z;
                acc[j].y += e.x * pa.y + e.y * pa.w + e.z * pb.y + e.w * pb.w;
            }
        }

        #pragma unroll
        for (int j = 0; j < 8; ++j) {
            if (toks[j] >= 0) {
                float2 v = make_float2(acc[j].x * SCALE, acc[j].y * SCALE);
                *(float2*)&out[(size_t)toks[j] * NEMBED + cs * 128 + 2 * lane] = v;
            }
        }
    }
}

// ------ bucket 1: D=256; P slice streamed through LDS in 16-row dbuf pieces -------
// cs in [0,4): cols [cs*256, +256). Block chunk = 32 tokens (8 waves x 4).
__device__ __forceinline__ void run_proj_stream(const int* __restrict__ x,
                                                const float* __restrict__ table,
                                                const float* __restrict__ proj,
                                                const int* __restrict__ list_b,
                                                float* __restrict__ out,
                                                int n, int start,
                                                int cs, int blk0, int nblk,
                                                float4* __restrict__ PL) {  // 2x1024 f4
    int tid = threadIdx.x, lane = tid & 63, w = tid >> 6;
    const float4* pj4 = (const float4*)proj;
    const float4* tb4 = (const float4*)table;
    int nch = (n + 31) >> 5;

    #pragma unroll 1
    for (int c = blk0; c < nch; c += nblk) {
        int toks[4], rows[4];
        #pragma unroll
        for (int j = 0; j < 4; ++j) {
            int i = c * 32 + w * 4 + j;
            toks[j] = rfl((i < n) ? list_b[i] : -1);
        }
        #pragma unroll
        for (int j = 0; j < 4; ++j)
            rows[j] = (toks[j] >= 0) ? rfl(x[toks[j]] - start) : 0;

        float4 acc[4];
        #pragma unroll
        for (int j = 0; j < 4; ++j) acc[j] = make_float4(0.f, 0.f, 0.f, 0.f);

        int i0 = tid * 2, i1 = tid * 2 + 1;
        // prologue: stage piece 0 -> buf 0
        float4 s0 = pj4[(size_t)(i0 >> 6) * 256 + cs * 64 + (i0 & 63)];
        float4 s1 = pj4[(size_t)(i1 >> 6) * 256 + cs * 64 + (i1 & 63)];
        PL[i0] = s0; PL[i1] = s1;
        __syncthreads();

        #pragma unroll 1
        for (int p = 0; p < 16; ++p) {
            const float4* cur = PL + (p & 1) * 1024;
            if (p < 15) {   // issue next-piece loads early (hidden under FMA)
                int base = (p + 1) * 16;
                s0 = pj4[(size_t)(base + (i0 >> 6)) * 256 + cs * 64 + (i0 & 63)];
                s1 = pj4[(size_t)(base + (i1 >> 6)) * 256 + cs * 64 + (i1 & 63)];
            }
            #pragma unroll 2
            for (int g = 0; g < 4; ++g) {
                float4 p0 = cur[(4 * g + 0) * 64 + lane];
                float4 p1 = cur[(4 * g + 1) * 64 + lane];
                float4 p2 = cur[(4 * g + 2) * 64 + lane];
                float4 p3 = cur[(4 * g + 3) * 64 + lane];
                #pragma unroll
                for (int j = 0; j < 4; ++j) {
                    float4 e = tb4[(size_t)rows[j] * 64 + p * 4 + g];  // wave-uniform
                    acc[j].x += e.x * p0.x + e.y * p1.x + e.z * p2.x + e.w * p3.x;
                    acc[j].y += e.x * p0.y + e.y * p1.y + e.z * p2.y + e.w * p3.y;
                    acc[j].z += e.x * p0.z + e.y * p1.z + e.z * p2.z + e.w * p3.z;
                    acc[j].w += e.x * p0.w + e.y * p1.w + e.z * p2.w + e.w * p3.w;
                }
            }
            if (p < 15) {   // commit next piece to the other buffer
                float4* nb = PL + ((p + 1) & 1) * 1024;
                nb[i0] = s0; nb[i1] = s1;
            }
            __syncthreads();
        }

        #pragma unroll
        for (int j = 0; j < 4; ++j) {
            if (toks[j] >= 0) {
                float4 v = acc[j];
                v.x *= SCALE; v.y *= SCALE; v.z *= SCALE; v.w *= SCALE;
                *(float4*)&out[(size_t)toks[j] * NEMBED + cs * 256 + lane * 4] = v;
            }
        }
    }
}

// ---------------- fused kernel: static block partition ----------------
__global__ __launch_bounds__(NTHREADS, 4)   // VGPR cap 128 (expect ~52); LDS 32 KB
void fused_embed_kernel(const int* __restrict__ x,
                        const float* __restrict__ t0, const float* __restrict__ t1,
                        const float* __restrict__ t2, const float* __restrict__ t3,
                        const float* __restrict__ p1, const float* __restrict__ p2,
                        const float* __restrict__ p3,
                        const int* __restrict__ cnt,
                        const int* __restrict__ lists,
                        float* __restrict__ out) {
    __shared__ __align__(16) float4 PL[2048];   // 32 KB
    int bid = blockIdx.x;
    int w = threadIdx.x >> 6;

    if (bid < G0) {
        run_copy(x, t0, lists, out, cnt[0], bid * 8 + w, G0 * 8);
    } else if (bid < G0 + G1) {
        int lb = bid - G0;
        run_proj_stream(x, t1, p1, lists + 1 * N_TOK, out, cnt[1], 20000,
                        lb & 3, lb >> 2, G1 / 4, PL);
    } else if (bid < G0 + G1 + G2) {
        int lb = bid - (G0 + G1);
        run_proj_reg<64>(x, t2, p2, lists + 2 * N_TOK, out, cnt[2], 40000,
                         lb & 7, (lb >> 3) * 8 + w, (G2 / 8) * 8, PL);
    } else {
        int lb = bid - (G0 + G1 + G2);
        run_proj_reg<16>(x, t3, p3, lists + 3 * N_TOK, out, cnt[3], 200000,
                         lb & 7, (lb >> 3) * 8 + w, (G3 / 8) * 8, PL);
    }
}

extern "C" void kernel_launch(void* const* d_in, const int* in_sizes, int n_in,
                              void* d_out, int out_size, void* d_ws, size_t ws_size,
                              hipStream_t stream) {
    const int*   x  = (const int*)d_in[0];
    const float* t0 = (const float*)d_in[1];
    const float* t1 = (const float*)d_in[2];
    const float* t2 = (const float*)d_in[3];
    const float* t3 = (const float*)d_in[4];
    const float* p1 = (const float*)d_in[5];
    const float* p2 = (const float*)d_in[6];
    const float* p3 = (const float*)d_in[7];
    float* out = (float*)d_out;

    int* cnt   = (int*)d_ws;
    int* lists = cnt + 64;

    hipMemsetAsync(d_ws, 0, 64 * sizeof(int), stream);
    classify_kernel<<<N_TOK / 256, 256, 0, stream>>>(x, cnt, lists);

    fused_embed_kernel<<<GRID, NTHREADS, 0, stream>>>(x, t0, t1, t2, t3, p1, p2, p3,
                                                      cnt, lists, out);
}

// Round 13
// 112.406 us; speedup vs baseline: 1.3038x; 1.0936x over previous
//
#include <hip/hip_runtime.h>

#define N_TOK    32768
#define NEMBED   1024
#define SCALE    32.0f   // sqrt(1024)
#define NTHREADS 512     // 8 waves per block

// 768 blocks = 3 blocks/CU (48 KB LDS each), one generation.
#define G0 20
#define G1 308   // %4==0 : b1 stream worker, cs x4, 77 chunks -> exactly 1 job/block
#define G2 392   // %8==0 : b2 coop worker, cs x8
#define G3 48    // %8==0 : b3 coop worker, cs x8
#define GRID (G0 + G1 + G2 + G3)   // 768

__device__ __forceinline__ int bucket_of(int idx) {
    return (idx < 20000) ? 0 : (idx < 40000) ? 1 : (idx < 200000) ? 2 : 3;
}
__device__ __forceinline__ int rfl(int v) { return __builtin_amdgcn_readfirstlane(v); }

// ---------------- classify + compact tokens into per-bucket lists ----------------
__global__ void classify_kernel(const int* __restrict__ x,
                                int* __restrict__ cnt,      // [4]
                                int* __restrict__ lists) {  // [4][N_TOK]
    __shared__ int s_cnt[4], s_base[4];
    int tid = threadIdx.x;
    if (tid < 4) s_cnt[tid] = 0;
    __syncthreads();
    int t = blockIdx.x * blockDim.x + tid;
    int b = 0, p = 0;
    if (t < N_TOK) {
        b = bucket_of(x[t]);
        p = atomicAdd(&s_cnt[b], 1);
    }
    __syncthreads();
    if (tid < 4) s_base[tid] = atomicAdd(&cnt[tid], s_cnt[tid]);
    __syncthreads();
    if (t < N_TOK) lists[b * N_TOK + s_base[b] + p] = t;
}

// ---------------- bucket 0: per-wave row copy (ids in SGPR, no LDS/barriers) ------
__device__ __forceinline__ void run_copy(const int* __restrict__ x,
                                         const float* __restrict__ table0,
                                         const int* __restrict__ list0,
                                         float* __restrict__ out,
                                         int n, int wv0, int nwv) {
    int lane = threadIdx.x & 63;
    const float4* t4 = (const float4*)table0;
    float4* o4 = (float4*)out;
    #pragma unroll 1
    for (int i = wv0; i < n; i += nwv) {
        int tok = rfl(list0[i]);
        int row = rfl(x[tok]);
        #pragma unroll
        for (int q = 0; q < 4; ++q) {
            float4 v = t4[(size_t)row * 256 + q * 64 + lane];
            v.x *= SCALE; v.y *= SCALE; v.z *= SCALE; v.w *= SCALE;
            o4[(size_t)tok * 256 + q * 64 + lane] = v;
        }
    }
}

// ------ buckets 2/3: P slice in LDS (pair layout) + E tile coop-staged in LDS ------
// cs in [0,8): cols [cs*128, +128); lane owns 2 cols (float2). Chunk = 64 tokens
// (8 waves x 8). Per-wave ids live in lanes 0..7 regs, distributed via __shfl.
// E gather is one batched coalesced round-trip per chunk (not 128 serial loads).
template <int D>
__device__ __forceinline__ void run_proj_coop(const int* __restrict__ x,
                                              const float* __restrict__ table,
                                              const float* __restrict__ proj,
                                              const int* __restrict__ list_b,
                                              float* __restrict__ out,
                                              int n, int start,
                                              int cs, int c0, int cstride,
                                              float4* __restrict__ PL,   // [D/2 * 64]
                                              float4* __restrict__ E4) { // [64 * D/4]
    constexpr int D4 = D / 4, D2 = D / 2;
    constexpr int NLOC = 8 * D4;              // E f4 per wave's 8 tokens
    int tid = threadIdx.x, lane = tid & 63, w = tid >> 6;
    const float4* tb4 = (const float4*)table;

    // one-time: stage P slice (pair layout: rows 2k2,2k2+1 x 2 cols per lane)
    #pragma unroll 1
    for (int idx = tid; idx < D2 * 64; idx += NTHREADS) {
        int k2 = idx >> 6, l = idx & 63;
        const float* r0 = &proj[(size_t)(2 * k2) * NEMBED + cs * 128 + 2 * l];
        const float* r1 = r0 + NEMBED;
        PL[idx] = make_float4(r0[0], r0[1], r1[0], r1[1]);
    }
    int nch = (n + 63) >> 6;
    if (c0 >= nch) return;   // block-uniform exit (no barrier executed afterwards)

    // ids(first chunk): lanes 0..7 hold this wave's 8 tokens
    int tok_l = -1, row_l = -1;
    if (lane < 8) {
        int i = c0 * 64 + w * 8 + lane;
        tok_l = (i < n) ? list_b[i] : -1;
        row_l = (tok_l >= 0) ? (x[tok_l] - start) : -1;
    }

    #pragma unroll 1
    for (int c = c0; c < nch; c += cstride) {
        // ---- stage E(c): wave-local coalesced gather via shfl'd rows
        #pragma unroll
        for (int q = 0; q < (NLOC + 63) / 64; ++q) {
            int il = q * 64 + lane;
            if (il < NLOC) {
                int tl = il / D4, el = il % D4;
                int row = __shfl(row_l, tl);
                E4[w * NLOC + il] = (row >= 0) ? tb4[(size_t)row * D4 + el]
                                               : make_float4(0.f, 0.f, 0.f, 0.f);
            }
        }
        // issue next-chunk list load (latency hides under barrier + compute)
        int ntok = -1, nc = c + cstride;
        if (lane < 8 && nc < nch) {
            int i = nc * 64 + w * 8 + lane;
            ntok = (i < n) ? list_b[i] : -1;
        }
        __syncthreads();   // E(c) visible (and P on first iteration)
        int nrow = (ntok >= 0) ? (x[ntok] - start) : -1;   // hides under FMA

        // ---- compute: pure LDS (P pair-reads + E broadcasts) + FMA
        float2 acc[8];
        #pragma unroll
        for (int j = 0; j < 8; ++j) acc[j] = make_float2(0.f, 0.f);
        #pragma unroll 2
        for (int kg = 0; kg < D4; ++kg) {
            float4 pa = PL[(2 * kg + 0) * 64 + lane];   // k rows 4kg, 4kg+1
            float4 pb = PL[(2 * kg + 1) * 64 + lane];   // k rows 4kg+2, 4kg+3
            #pragma unroll
            for (int j = 0; j < 8; ++j) {
                float4 e = E4[(w * 8 + j) * D4 + kg];   // wave-uniform broadcast
                acc[j].x += e.x * pa.x + e.y * pa.z + e.z * pb.x + e.w * pb.z;
                acc[j].y += e.x * pa.y + e.y * pa.w + e.z * pb.y + e.w * pb.w;
            }
        }
        #pragma unroll
        for (int j = 0; j < 8; ++j) {
            int tok = __shfl(tok_l, j);
            if (tok >= 0) {
                float2 v = make_float2(acc[j].x * SCALE, acc[j].y * SCALE);
                *(float2*)&out[(size_t)tok * NEMBED + cs * 128 + 2 * lane] = v;
            }
        }
        __syncthreads();   // E buffer free for next stage
        tok_l = ntok; row_l = nrow;
    }
}

// ------ bucket 1: D=256; P slice streamed through LDS in 16-row dbuf pieces -------
// cs in [0,4): cols [cs*256, +256). Block chunk = 32 tokens (8 waves x 4).
__device__ __forceinline__ void run_proj_stream(const int* __restrict__ x,
                                                const float* __restrict__ table,
                                                const float* __restrict__ proj,
                                                const int* __restrict__ list_b,
                                                float* __restrict__ out,
                                                int n, int start,
                                                int cs, int blk0, int nblk,
                                                float4* __restrict__ PL) {  // 2x1024 f4
    int tid = threadIdx.x, lane = tid & 63, w = tid >> 6;
    const float4* pj4 = (const float4*)proj;
    const float4* tb4 = (const float4*)table;
    int nch = (n + 31) >> 5;

    #pragma unroll 1
    for (int c = blk0; c < nch; c += nblk) {
        int toks[4], rows[4];
        #pragma unroll
        for (int j = 0; j < 4; ++j) {
            int i = c * 32 + w * 4 + j;
            toks[j] = rfl((i < n) ? list_b[i] : -1);
        }
        #pragma unroll
        for (int j = 0; j < 4; ++j)
            rows[j] = (toks[j] >= 0) ? rfl(x[toks[j]] - start) : 0;

        float4 acc[4];
        #pragma unroll
        for (int j = 0; j < 4; ++j) acc[j] = make_float4(0.f, 0.f, 0.f, 0.f);

        int i0 = tid * 2, i1 = tid * 2 + 1;
        float4 s0 = pj4[(size_t)(i0 >> 6) * 256 + cs * 64 + (i0 & 63)];
        float4 s1 = pj4[(size_t)(i1 >> 6) * 256 + cs * 64 + (i1 & 63)];
        PL[i0] = s0; PL[i1] = s1;
        __syncthreads();

        #pragma unroll 1
        for (int p = 0; p < 16; ++p) {
            const float4* cur = PL + (p & 1) * 1024;
            if (p < 15) {
                int base = (p + 1) * 16;
                s0 = pj4[(size_t)(base + (i0 >> 6)) * 256 + cs * 64 + (i0 & 63)];
                s1 = pj4[(size_t)(base + (i1 >> 6)) * 256 + cs * 64 + (i1 & 63)];
            }
            #pragma unroll 2
            for (int g = 0; g < 4; ++g) {
                float4 p0 = cur[(4 * g + 0) * 64 + lane];
                float4 p1 = cur[(4 * g + 1) * 64 + lane];
                float4 p2 = cur[(4 * g + 2) * 64 + lane];
                float4 p3 = cur[(4 * g + 3) * 64 + lane];
                #pragma unroll
                for (int j = 0; j < 4; ++j) {
                    float4 e = tb4[(size_t)rows[j] * 64 + p * 4 + g];  // wave-uniform
                    acc[j].x += e.x * p0.x + e.y * p1.x + e.z * p2.x + e.w * p3.x;
                    acc[j].y += e.x * p0.y + e.y * p1.y + e.z * p2.y + e.w * p3.y;
                    acc[j].z += e.x * p0.z + e.y * p1.z + e.z * p2.z + e.w * p3.z;
                    acc[j].w += e.x * p0.w + e.y * p1.w + e.z * p2.w + e.w * p3.w;
                }
            }
            if (p < 15) {
                float4* nb = PL + ((p + 1) & 1) * 1024;
                nb[i0] = s0; nb[i1] = s1;
            }
            __syncthreads();
        }

        #pragma unroll
        for (int j = 0; j < 4; ++j) {
            if (toks[j] >= 0) {
                float4 v = acc[j];
                v.x *= SCALE; v.y *= SCALE; v.z *= SCALE; v.w *= SCALE;
                *(float4*)&out[(size_t)toks[j] * NEMBED + cs * 256 + lane * 4] = v;
            }
        }
    }
}

// ---------------- fused kernel: static block partition ----------------
__global__ __launch_bounds__(NTHREADS, 4)
void fused_embed_kernel(const int* __restrict__ x,
                        const float* __restrict__ t0, const float* __restrict__ t1,
                        const float* __restrict__ t2, const float* __restrict__ t3,
                        const float* __restrict__ p1, const float* __restrict__ p2,
                        const float* __restrict__ p3,
                        const int* __restrict__ cnt,
                        const int* __restrict__ lists,
                        float* __restrict__ out) {
    // 48 KB: b2 = P[2048 f4] + E[1024 f4]; b3 = P[512] + E[256]; b1 = P dbuf[2048]
    __shared__ __align__(16) float4 SM[3072];
    int bid = blockIdx.x;
    int w = threadIdx.x >> 6;

    if (bid < G0) {
        run_copy(x, t0, lists, out, cnt[0], bid * 8 + w, G0 * 8);
    } else if (bid < G0 + G1) {
        int lb = bid - G0;
        run_proj_stream(x, t1, p1, lists + 1 * N_TOK, out, cnt[1], 20000,
                        lb & 3, lb >> 2, G1 / 4, SM);
    } else if (bid < G0 + G1 + G2) {
        int lb = bid - (G0 + G1);
        run_proj_coop<64>(x, t2, p2, lists + 2 * N_TOK, out, cnt[2], 40000,
                          lb & 7, lb >> 3, G2 / 8, SM, SM + 2048);
    } else {
        int lb = bid - (G0 + G1 + G2);
        run_proj_coop<16>(x, t3, p3, lists + 3 * N_TOK, out, cnt[3], 200000,
                          lb & 7, lb >> 3, G3 / 8, SM, SM + 512);
    }
}

extern "C" void kernel_launch(void* const* d_in, const int* in_sizes, int n_in,
                              void* d_out, int out_size, void* d_ws, size_t ws_size,
                              hipStream_t stream) {
    const int*   x  = (const int*)d_in[0];
    const float* t0 = (const float*)d_in[1];
    const float* t1 = (const float*)d_in[2];
    const float* t2 = (const float*)d_in[3];
    const float* t3 = (const float*)d_in[4];
    const float* p1 = (const float*)d_in[5];
    const float* p2 = (const float*)d_in[6];
    const float* p3 = (const float*)d_in[7];
    float* out = (float*)d_out;

    int* cnt   = (int*)d_ws;
    int* lists = cnt + 64;

    hipMemsetAsync(d_ws, 0, 64 * sizeof(int), stream);
    classify_kernel<<<N_TOK / 256, 256, 0, stream>>>(x, cnt, lists);

    fused_embed_kernel<<<GRID, NTHREADS, 0, stream>>>(x, t0, t1, t2, t3, p1, p2, p3,
                                                      cnt, lists, out);
}

// Round 14
// 85.830 us; speedup vs baseline: 1.7075x; 1.3096x over previous
//
#include <hip/hip_runtime.h>

#define N_TOK    32768
#define NEMBED   1024
#define SCALE    32.0f   // sqrt(1024)
#define NTHREADS 512     // 8 waves per block

// grid partitioned by output volume (write-BW is the floor):
#define G0 60
#define G1 80    // %4==0 : b1 (K=256, P streamed in pieces), 1 chunk/block
#define G2 308   // %4==0 : b2 (D=64), ~2 wave-jobs/wave
#define G3 128   // %4==0 : b3 (D=16), ~2 wave-jobs/wave
#define GRID (G0 + G1 + G2 + G3)   // 576

typedef __attribute__((ext_vector_type(8))) short bf16x8;   // 8 bf16 = 4 VGPR
typedef __attribute__((ext_vector_type(4))) float f32x4;    // MFMA acc

__device__ __forceinline__ int bucket_of(int idx) {
    return (idx < 20000) ? 0 : (idx < 40000) ? 1 : (idx < 200000) ? 2 : 3;
}

__device__ __forceinline__ unsigned pk(float a, float b) {   // 2xf32 -> packed bf16 pair (truncate)
    return (__float_as_uint(a) >> 16) | (__float_as_uint(b) & 0xffff0000u);
}
union ABu { bf16x8 v; unsigned u[4]; };
__device__ __forceinline__ bf16x8 make_frag(const float* p) {  // 8 consecutive f32 -> bf16x8
    float4 e0 = *(const float4*)p;
    float4 e1 = *(const float4*)(p + 4);
    ABu a;
    a.u[0] = pk(e0.x, e0.y); a.u[1] = pk(e0.z, e0.w);
    a.u[2] = pk(e1.x, e1.y); a.u[3] = pk(e1.z, e1.w);
    return a.v;
}
__device__ __forceinline__ bf16x8 zero_frag() {
    ABu a; a.u[0] = a.u[1] = a.u[2] = a.u[3] = 0u; return a.v;
}

// ---------------- classify + compact tokens into per-bucket lists ----------------
__global__ void classify_kernel(const int* __restrict__ x,
                                int* __restrict__ cnt,      // [4]
                                int* __restrict__ lists) {  // [4][N_TOK]
    __shared__ int s_cnt[4], s_base[4];
    int tid = threadIdx.x;
    if (tid < 4) s_cnt[tid] = 0;
    __syncthreads();
    int t = blockIdx.x * blockDim.x + tid;
    int b = 0, p = 0;
    if (t < N_TOK) {
        b = bucket_of(x[t]);
        p = atomicAdd(&s_cnt[b], 1);
    }
    __syncthreads();
    if (tid < 4) s_base[tid] = atomicAdd(&cnt[tid], s_cnt[tid]);
    __syncthreads();
    if (t < N_TOK) lists[b * N_TOK + s_base[b] + p] = t;
}

// ---------------- bucket 0: per-wave row copy ----------------
__device__ __forceinline__ void run_copy(const int* __restrict__ x,
                                         const float* __restrict__ table0,
                                         const int* __restrict__ list0,
                                         float* __restrict__ out,
                                         int n, int wv0, int nwv) {
    int lane = threadIdx.x & 63;
    const float4* t4 = (const float4*)table0;
    float4* o4 = (float4*)out;
    #pragma unroll 1
    for (int i = wv0; i < n; i += nwv) {
        int tok = __builtin_amdgcn_readfirstlane(list0[i]);
        int row = __builtin_amdgcn_readfirstlane(x[tok]);
        #pragma unroll
        for (int q = 0; q < 4; ++q) {
            float4 v = t4[(size_t)row * 256 + q * 64 + lane];
            v.x *= SCALE; v.y *= SCALE; v.z *= SCALE; v.w *= SCALE;
            o4[(size_t)tok * 256 + q * 64 + lane] = v;
        }
    }
}

// ---- buckets 2/3: MFMA worker. P slice (cs of 4, 256 cols) packed fragment-major
// in LDS once per block; then barrier-free per-wave jobs of 16 tokens x 256 cols.
template <int D>   // 64 or 16
__device__ void run_proj_mfma(const int* __restrict__ x,
                              const float* __restrict__ table,
                              const float* __restrict__ proj,
                              const int* __restrict__ list_b,
                              float* __restrict__ out,
                              int n, int start, int cs,
                              int wj0, int wjs, char* __restrict__ PL) {
    constexpr int KS = (D + 31) / 32;      // k-steps: 2 (D=64) / 1 (D=16, zero-padded)
    int tid = threadIdx.x, lane = tid & 63;

    // ---- pack P[k][col] f32 -> PL[ks][nt][lane][j] bf16 (b-frag order)
    constexpr int ITEMS = KS * 2048;       // 8-byte units
    #pragma unroll 1
    for (int it = tid; it < ITEMS; it += NTHREADS) {
        int j0 = (it & 1) * 4;
        int ln = (it >> 1) & 63;
        int nt = (it >> 7) & 15;
        int ks = it >> 11;
        int kb = ks * 32 + ((ln >> 4) << 3) + j0;
        int col = cs * 256 + nt * 16 + (ln & 15);
        float f0 = (kb + 0 < D) ? proj[(size_t)(kb + 0) * NEMBED + col] : 0.f;
        float f1 = (kb + 1 < D) ? proj[(size_t)(kb + 1) * NEMBED + col] : 0.f;
        float f2 = (kb + 2 < D) ? proj[(size_t)(kb + 2) * NEMBED + col] : 0.f;
        float f3 = (kb + 3 < D) ? proj[(size_t)(kb + 3) * NEMBED + col] : 0.f;
        *(uint2*)(PL + (((ks * 16 + nt) * 64 + ln) << 4) + j0 * 2) =
            make_uint2(pk(f0, f1), pk(f2, f3));
    }
    __syncthreads();

    int nmt = (n + 15) >> 4;
    #pragma unroll 1
    for (int mt = wj0; mt < nmt; mt += wjs) {
        int ia = mt * 16 + (lane & 15);
        int tok_a = (ia < n) ? list_b[ia] : -1;
        int row_a = (tok_a >= 0) ? (x[tok_a] - start) : 0;
        const float* rp = table + (size_t)row_a * D;
        int k0 = (lane >> 4) << 3;
        bf16x8 a0 = (k0 < D) ? make_frag(rp + k0) : zero_frag();
        f32x4 acc[16];
        #pragma unroll
        for (int nt = 0; nt < 16; ++nt) acc[nt] = f32x4{0.f, 0.f, 0.f, 0.f};
        #pragma unroll
        for (int nt = 0; nt < 16; ++nt) {
            bf16x8 b = *(const bf16x8*)(PL + ((nt * 64 + lane) << 4));
            acc[nt] = __builtin_amdgcn_mfma_f32_16x16x32_bf16(a0, b, acc[nt], 0, 0, 0);
        }
        if constexpr (KS == 2) {
            bf16x8 a1 = make_frag(rp + 32 + k0);
            #pragma unroll
            for (int nt = 0; nt < 16; ++nt) {
                bf16x8 b = *(const bf16x8*)(PL + (((16 + nt) * 64 + lane) << 4));
                acc[nt] = __builtin_amdgcn_mfma_f32_16x16x32_bf16(a1, b, acc[nt], 0, 0, 0);
            }
        }
        // D-frag: row = (lane>>4)*4 + r, col = lane&15 (m89-verified)
        int tokd[4];
        #pragma unroll
        for (int r = 0; r < 4; ++r) tokd[r] = __shfl(tok_a, ((lane >> 4) << 2) + r);
        #pragma unroll
        for (int r = 0; r < 4; ++r) {
            if (tokd[r] >= 0) {
                float* op = out + (size_t)tokd[r] * NEMBED + cs * 256 + (lane & 15);
                #pragma unroll
                for (int nt = 0; nt < 16; ++nt) op[nt * 16] = acc[nt][r] * SCALE;
            }
        }
    }
}

// ---- bucket 1: K=256 MFMA, P streamed through LDS in 4 fragment-packed pieces ----
__device__ void run_proj_mfma_big(const int* __restrict__ x,
                                  const float* __restrict__ table,
                                  const float* __restrict__ proj,
                                  const int* __restrict__ list_b,
                                  float* __restrict__ out,
                                  int n, int start, int cs,
                                  int c0, int cstr, char* __restrict__ PL) {
    int tid = threadIdx.x, lane = tid & 63, w = tid >> 6;
    int nch = (n + 127) >> 7;
    #pragma unroll 1
    for (int c = c0; c < nch; c += cstr) {
        int ia = c * 128 + w * 16 + (lane & 15);
        int tok_a = (ia < n) ? list_b[ia] : -1;
        int row_a = (tok_a >= 0) ? (x[tok_a] - start) : 0;
        const float* rp = table + (size_t)row_a * 256;
        f32x4 acc[16];
        #pragma unroll
        for (int nt = 0; nt < 16; ++nt) acc[nt] = f32x4{0.f, 0.f, 0.f, 0.f};

        #pragma unroll 1
        for (int piece = 0; piece < 4; ++piece) {
            __syncthreads();   // previous piece fully consumed
            #pragma unroll 1
            for (int it = tid; it < 4096; it += NTHREADS) {
                int j0 = (it & 1) * 4;
                int ln = (it >> 1) & 63;
                int nt = (it >> 7) & 15;
                int ks = it >> 11;
                int kb = piece * 64 + ks * 32 + ((ln >> 4) << 3) + j0;
                int col = cs * 256 + nt * 16 + (ln & 15);
                float f0 = proj[(size_t)(kb + 0) * NEMBED + col];
                float f1 = proj[(size_t)(kb + 1) * NEMBED + col];
                float f2 = proj[(size_t)(kb + 2) * NEMBED + col];
                float f3 = proj[(size_t)(kb + 3) * NEMBED + col];
                *(uint2*)(PL + (((ks * 16 + nt) * 64 + ln) << 4) + j0 * 2) =
                    make_uint2(pk(f0, f1), pk(f2, f3));
            }
            __syncthreads();
            int k0 = (lane >> 4) << 3;
            bf16x8 a0 = make_frag(rp + piece * 64 + k0);
            bf16x8 a1 = make_frag(rp + piece * 64 + 32 + k0);
            #pragma unroll
            for (int nt = 0; nt < 16; ++nt) {
                bf16x8 b = *(const bf16x8*)(PL + ((nt * 64 + lane) << 4));
                acc[nt] = __builtin_amdgcn_mfma_f32_16x16x32_bf16(a0, b, acc[nt], 0, 0, 0);
            }
            #pragma unroll
            for (int nt = 0; nt < 16; ++nt) {
                bf16x8 b = *(const bf16x8*)(PL + (((16 + nt) * 64 + lane) << 4));
                acc[nt] = __builtin_amdgcn_mfma_f32_16x16x32_bf16(a1, b, acc[nt], 0, 0, 0);
            }
        }
        int tokd[4];
        #pragma unroll
        for (int r = 0; r < 4; ++r) tokd[r] = __shfl(tok_a, ((lane >> 4) << 2) + r);
        #pragma unroll
        for (int r = 0; r < 4; ++r) {
            if (tokd[r] >= 0) {
                float* op = out + (size_t)tokd[r] * NEMBED + cs * 256 + (lane & 15);
                #pragma unroll
                for (int nt = 0; nt < 16; ++nt) op[nt * 16] = acc[nt][r] * SCALE;
            }
        }
    }
}

// ---------------- fused kernel: static block partition ----------------
__global__ __launch_bounds__(NTHREADS, 4)
void fused_embed_kernel(const int* __restrict__ x,
                        const float* __restrict__ t0, const float* __restrict__ t1,
                        const float* __restrict__ t2, const float* __restrict__ t3,
                        const float* __restrict__ p1, const float* __restrict__ p2,
                        const float* __restrict__ p3,
                        const int* __restrict__ cnt,
                        const int* __restrict__ lists,
                        float* __restrict__ out) {
    __shared__ __align__(16) char PL[32768];   // 32 KB fragment-packed P
    int bid = blockIdx.x;
    int w = threadIdx.x >> 6;

    if (bid < G0) {
        run_copy(x, t0, lists, out, cnt[0], bid * 8 + w, G0 * 8);
    } else if (bid < G0 + G1) {
        int lb = bid - G0;
        run_proj_mfma_big(x, t1, p1, lists + 1 * N_TOK, out, cnt[1], 20000,
                          lb & 3, lb >> 2, G1 / 4, PL);
    } else if (bid < G0 + G1 + G2) {
        int lb = bid - (G0 + G1);
        run_proj_mfma<64>(x, t2, p2, lists + 2 * N_TOK, out, cnt[2], 40000,
                          lb & 3, (lb >> 2) * 8 + w, (G2 / 4) * 8, PL);
    } else {
        int lb = bid - (G0 + G1 + G2);
        run_proj_mfma<16>(x, t3, p3, lists + 3 * N_TOK, out, cnt[3], 200000,
                          lb & 3, (lb >> 2) * 8 + w, (G3 / 4) * 8, PL);
    }
}

extern "C" void kernel_launch(void* const* d_in, const int* in_sizes, int n_in,
                              void* d_out, int out_size, void* d_ws, size_t ws_size,
                              hipStream_t stream) {
    const int*   x  = (const int*)d_in[0];
    const float* t0 = (const float*)d_in[1];
    const float* t1 = (const float*)d_in[2];
    const float* t2 = (const float*)d_in[3];
    const float* t3 = (const float*)d_in[4];
    const float* p1 = (const float*)d_in[5];
    const float* p2 = (const float*)d_in[6];
    const float* p3 = (const float*)d_in[7];
    float* out = (float*)d_out;

    int* cnt   = (int*)d_ws;
    int* lists = cnt + 64;

    hipMemsetAsync(d_ws, 0, 64 * sizeof(int), stream);
    classify_kernel<<<N_TOK / 256, 256, 0, stream>>>(x, cnt, lists);

    fused_embed_kernel<<<GRID, NTHREADS, 0, stream>>>(x, t0, t1, t2, t3, p1, p2, p3,
                                                      cnt, lists, out);
}